// Round 16
// baseline (33.119 us; speedup 1.0000x reference)
//
#include <hip/hip_runtime.h>

#define TT   512
#define BB   4
#define OUTL 261632        // per-batch trimmed output length

typedef __attribute__((ext_vector_type(8))) short short8;
typedef __attribute__((ext_vector_type(4))) float f32x4;

__device__ __forceinline__ unsigned short f2bf(float x) {
    union { float f; unsigned int u; } v; v.f = x;
    unsigned int r = v.u + 0x7fffu + ((v.u >> 16) & 1u);   // RNE
    return (unsigned short)(r >> 16);
}
__device__ __forceinline__ unsigned int pack2(float lo, float hi) {
    return ((unsigned int)f2bf(hi) << 16) | (unsigned int)f2bf(lo);
}
__device__ __forceinline__ short8 ld8(const unsigned int* p) {
    return *reinterpret_cast<const short8*>(p);
}
__device__ __forceinline__ short8 mk8(unsigned int a, unsigned int b,
                                      unsigned int c, unsigned int d) {
    union { uint4 u; short8 s; } v; v.u = make_uint4(a, b, c, d); return v.s;
}

// ---- prep_k: DFT coefficient matrices (bf16 pairs) to global (r14-proven) ----
__global__ __launch_bounds__(256) void prep_k(unsigned int* __restrict__ B1g,
                                              unsigned int* __restrict__ B2g) {
    int tid = blockIdx.x * 256 + threadIdx.x;
    if (tid < 2048) {                      // B1g[n<64][j=f2<32]
        int n = tid >> 5, j = tid & 31, n2b = n & 31;
        float ang = (float)((n2b * j) & 31) * 0.19634954084936207f;   // 2pi/32
        float co = __cosf(ang), si = __sinf(ang);
        B1g[n * 32 + j] = (n < 32) ? pack2(co, -si) : pack2(si, co);
    }
    int t2 = tid - 2048;
    if (t2 >= 0 && t2 < 4096) {            // B2g[n1<64][f1<64]
        int n1 = t2 >> 6, f1 = t2 & 63;
        float ang = (float)((n1 * f1) & 63) * 0.09817477042468103f;   // 2pi/64
        B2g[n1 * 64 + f1] = pack2(__cosf(ang), -__sinf(ang));
    }
}

// Fused iSTFT (r15 math, residency-lean): one block = 4 t-columns, one per wave.
// 2048-pt inverse DFT = stage1 MFMA -> in-reg twiddle -> stage2 MFMA, fused
// per K-slice kk (only 48 acc VGPRs live); B fragments streamed from L1-hot
// global tables; 32KB LDS -> 4-5 blocks/CU.
__global__ __launch_bounds__(256, 4) void istft_k(const float* __restrict__ X,
                                                  const unsigned int* __restrict__ B1g,
                                                  const unsigned int* __restrict__ B2g,
                                                  const float* __restrict__ win,
                                                  float* __restrict__ out) {
    __shared__ unsigned int tile[8192];    // 32 KB: staged cols -> frames

    const int S  = blockIdx.x;             // 0..511
    const int L  = ((S & 7) << 6) | (S >> 3);   // XCD x owns contiguous tiles
    const int c0 = L * 4;
    const int b  = c0 >> 9;
    const int t0 = c0 & 511;               // multiple of 4
    const int tid = threadIdx.x;
    const int w = tid >> 6, l = tid & 63;
    const int sI = l & 15, h = l >> 4;

    // ---- stage 4 columns: coalesced float4 line loads, bf16-pack ----
    // tile[f*4 + slot], slot = (c + f) & 3 (bank rotation)
    const float* Xb = X + ((size_t)(b * 2048) * 512 + t0) * 2;
    #pragma unroll
    for (int it = 0; it < 16; it++) {
        int idx = it * 256 + tid;          // 0..4095
        int f = idx >> 1, q = idx & 1;
        float4 v = *reinterpret_cast<const float4*>(Xb + ((size_t)f * 512 + 2 * q) * 2);
        tile[f * 4 + ((2 * q + f) & 3)]     = pack2(v.x, v.y);
        tile[f * 4 + ((2 * q + 1 + f) & 3)] = pack2(v.z, v.w);
    }
    __syncthreads();

    // ---- fused stage1 + twiddle + stage2, one K-slice (kk) at a time ----
    const int slot = (w + sI) & 3;
    f32x4 acc2[2][4] = {};
    #pragma unroll
    for (int kk = 0; kk < 4; kk++) {
        // A-fragments for stage-1 row block f1 = 16*kk + sI
        int f1r = 16 * kk + sI;
        short8 af[2];
        #pragma unroll
        for (int k1 = 0; k1 < 2; k1++) {
            int f2b = 16 * k1 + 4 * h;
            af[k1] = mk8(tile[(f1r + 64 * (f2b + 0)) * 4 + slot],
                         tile[(f1r + 64 * (f2b + 1)) * 4 + slot],
                         tile[(f1r + 64 * (f2b + 2)) * 4 + slot],
                         tile[(f1r + 64 * (f2b + 3)) * 4 + slot]);
        }
        // stage 1: G[f1-block kk][n] for all 64 n (4 ni frags)
        f32x4 acck[4] = {};
        #pragma unroll
        for (int ni = 0; ni < 4; ni++)
            #pragma unroll
            for (int k1 = 0; k1 < 2; k1++)
                acck[ni] = __builtin_amdgcn_mfma_f32_16x16x32_bf16(
                    af[k1], ld8(&B1g[(16 * ni + sI) * 32 + 16 * k1 + 4 * h]),
                    acck[ni], 0, 0, 0);
        // in-register twiddle (lane's own stage-1 output == its stage-2 A frag)
        #pragma unroll
        for (int mi2 = 0; mi2 < 2; mi2++) {
            const int n2 = 16 * mi2 + sI;
            unsigned int u0, u1, u2, u3;
            #pragma unroll
            for (int j = 0; j < 4; j++) {
                int f1 = 16 * kk + 4 * h + j;
                float Gre = acck[mi2][j];
                float Gim = acck[mi2 + 2][j];
                float ang = (float)((n2 * f1) & 2047) * 0.0030679615757712823f; // 2pi/2048
                float co = __cosf(ang), si = __sinf(ang);
                unsigned int pv = pack2(Gre * co - Gim * si, Gre * si + Gim * co);
                if (j == 0) u0 = pv; else if (j == 1) u1 = pv;
                else if (j == 2) u2 = pv; else u3 = pv;
            }
            short8 a2f = mk8(u0, u1, u2, u3);
            #pragma unroll
            for (int ni = 0; ni < 4; ni++)
                acc2[mi2][ni] = __builtin_amdgcn_mfma_f32_16x16x32_bf16(
                    a2f, ld8(&B2g[(16 * ni + sI) * 64 + 16 * kk + 4 * h]),
                    acc2[mi2][ni], 0, 0, 0);
        }
    }
    __syncthreads();                       // all waves done reading tile

    // ---- window + pack frames: frames[w][1024] u32 over tile[0..4096) ----
    unsigned int* fw = tile + w * 1024;
    #pragma unroll
    for (int mi2 = 0; mi2 < 2; mi2++)
        #pragma unroll
        for (int ni = 0; ni < 4; ni++) {
            int n1 = 16 * ni + sI;
            #pragma unroll
            for (int rp = 0; rp < 2; rp++) {
                int n2a = 16 * mi2 + 4 * h + 2 * rp;
                int na  = n2a + 32 * n1;
                float w0 = 0.5f - 0.5f * __cosf((float)na * 0.0030679615757712823f);
                float w1 = 0.5f - 0.5f * __cosf((float)(na + 1) * 0.0030679615757712823f);
                fw[(n2a >> 1) + 16 * n1] =
                    pack2(acc2[mi2][ni][2 * rp] * w0, acc2[mi2][ni][2 * rp + 1] * w1);
            }
        }
    __syncthreads();

    // ---- OLA over untrimmed [t0*512, t0*512+3584) (r15/r8-proven) ----
    const bool interior = (t0 >= 3) && (t0 <= 505);
    float invw0 = 0.f, invw1 = 0.f;
    {
        float s0 = 0.f, s1 = 0.f;
        #pragma unroll
        for (int k = 0; k < 4; k++) {
            float a = win[tid + 512 * k];
            float c = win[tid + 256 + 512 * k];
            s0 += a * a; s1 += c * c;
        }
        invw0 = 1.0f / (2048.0f * s0);
        invw1 = 1.0f / (2048.0f * s1);
    }
    float* outb = out + (size_t)b * OUTL;
    #pragma unroll 1
    for (int qi = 0; qi < 14; qi++) {
        int jl = tid + 256 * qi;           // 0..3583
        int tb_l = jl >> 9, rr = jl & 511;
        float sum = 0.f;
        #pragma unroll
        for (int k = 0; k < 4; k++) {
            int m = tb_l - k;
            if (m >= 0 && m < 4) {
                int n = rr + (k << 9);
                unsigned int v = tile[m * 1024 + (n >> 1)];
                union { unsigned int u; float f; } cv;
                cv.u = ((n & 1) ? (v >> 16) : (v & 0xffffu)) << 16;
                sum += cv.f;
            }
        }
        int j  = t0 * 512 + jl;
        int jp = j - 1024;
        if (jp < 0 || jp >= OUTL) continue;
        float y;
        if (interior) {
            y = sum * ((qi & 1) ? invw1 : invw0);
        } else {
            int tb = j >> 9;
            float s = 0.f;
            #pragma unroll
            for (int k = 0; k < 4; k++) {
                int t = tb - k;
                if (t >= 0 && t < TT) { float ww = win[rr + (k << 9)]; s += ww * ww; }
            }
            y = sum * (1.0f / 2048.0f);
            if (s > 1e-10f) y /= s;
        }
        if (jl >= 1536 && jl < 2048) outb[jp] = y;     // unique-writer core
        else                         atomicAdd(outb + jp, y);
    }
}

extern "C" void kernel_launch(void* const* d_in, const int* in_sizes, int n_in,
                              void* d_out, int out_size, void* d_ws, size_t ws_size,
                              hipStream_t stream) {
    const float* X  = (const float*)d_in[0];
    const float* w  = (const float*)d_in[3];
    float* out = (float*)d_out;

    unsigned int* B1g = (unsigned int*)d_ws;           // 8 KB
    unsigned int* B2g = B1g + 2048;                    // 16 KB

    hipMemsetAsync(out, 0, (size_t)out_size * sizeof(float), stream);
    prep_k<<<dim3(24), dim3(256), 0, stream>>>(B1g, B2g);
    istft_k<<<dim3(BB * TT / 4), dim3(256), 0, stream>>>(X, B1g, B2g, w, out);
}